// Round 4
// baseline (227.766 us; speedup 1.0000x reference)
//
#include <hip/hip_runtime.h>
#include <math.h>

#define HDIM 4096
#define NEXP 64
#define NTOK 8192
#define KSPLIT 8
#define KSLICE (HDIM / KSPLIT)   // 512
#define NCHUNK (KSLICE / 32)     // 16 chunks of K=32 per slice
#define NKC (HDIM / 32)          // 128 global k-chunks
#define AUXF 1024                // floats reserved for 8 auxbuf copies
#define TPW 2                    // tokens per wave in topk_k
// B-split layout (shorts): [term][kc 128][quad 4][n 64][8]
#define BT_TERM (NKC * 4 * 64 * 8)  // 262144 shorts per term
#define BT_KC (4 * 64 * 8)          // 2048 shorts per k-chunk

typedef short short8 __attribute__((ext_vector_type(8)));
typedef float f32x4 __attribute__((ext_vector_type(4)));

union i4s8 { int4 i; short8 s; };

// Exact 3-way bf16 split of two fp32 values, packed as (lo16=x0, hi16=x1).
__device__ __forceinline__ void split2x3(float x0, float x1, int& h, int& md, int& lo) {
  unsigned u0 = __float_as_uint(x0), u1 = __float_as_uint(x1);
  unsigned h0 = u0 & 0xFFFF0000u, h1 = u1 & 0xFFFF0000u;
  float r0 = x0 - __uint_as_float(h0);
  float r1 = x1 - __uint_as_float(h1);
  unsigned m0 = __float_as_uint(r0) & 0xFFFF0000u;
  unsigned m1 = __float_as_uint(r1) & 0xFFFF0000u;
  float s0 = r0 - __uint_as_float(m0);
  float s1 = r1 - __uint_as_float(m1);
  h  = (int)((h0 >> 16) | h1);
  md = (int)((m0 >> 16) | m1);
  lo = (int)((__float_as_uint(s0) >> 16) | (__float_as_uint(s1) & 0xFFFF0000u));
}

__device__ __forceinline__ void split8(const float4& p0, const float4& p1,
                                       short8& h8, short8& m8, short8& l8) {
  i4s8 h, m, l;
  split2x3(p0.x, p0.y, h.i.x, m.i.x, l.i.x);
  split2x3(p0.z, p0.w, h.i.y, m.i.y, l.i.y);
  split2x3(p1.x, p1.y, h.i.z, m.i.z, l.i.z);
  split2x3(p1.z, p1.w, h.i.w, m.i.w, l.i.w);
  h8 = h.s; m8 = m.s; l8 = l.s;
}

// ---------------------------------------------------------------------------
// Prep: (a) blocks 0..127 pre-split W (64x4096 fp32) into MFMA-fragment-
// ordered bf16x3 terms; (b) block 128 zeroes the aux accumulators.
// ---------------------------------------------------------------------------
__global__ __launch_bounds__(256) void prep_k(const float* __restrict__ W,
                                              short* __restrict__ Bs,
                                              float* __restrict__ auxbuf) {
  if (blockIdx.x == 128) {
#pragma unroll
    for (int j = 0; j < 4; ++j) auxbuf[j * 256 + threadIdx.x] = 0.f;
    return;
  }
  const int g = blockIdx.x * 256 + threadIdx.x;  // 0..32767
  const int n = g >> 9;                          // expert 0..63
  const int k8 = g & 511;                        // 8-k group
  const float4 p0 = *(const float4*)&W[(size_t)n * HDIM + k8 * 8];
  const float4 p1 = *(const float4*)&W[(size_t)n * HDIM + k8 * 8 + 4];
  short8 h8, m8, l8;
  split8(p0, p1, h8, m8, l8);
  const int kc = k8 >> 2, quad = k8 & 3;
  const size_t o = (((size_t)kc * 4 + quad) * 64 + n) * 8;
  *(short8*)&Bs[o] = h8;
  *(short8*)&Bs[o + BT_TERM] = m8;
  *(short8*)&Bs[o + 2 * BT_TERM] = l8;
}

// ---------------------------------------------------------------------------
// LDS-free GEMM: logits[t][e] = hidden[t][:] . gate_w[e][:], bf16x3 MFMA.
// Each wave: 32 tokens x 64 experts over one K-slice of 512. A fragments
// loaded straight from global (float4 x2 per lane = the exact 16x16x32
// A-fragment), split in-register; B fragments pre-split (prep_k) and loaded
// as plain dwordx4 (L2-resident, 1.5 MB). No LDS, no barriers -> free
// compiler pipelining; register double-buffer prefetch on A.
// ---------------------------------------------------------------------------
__global__ __launch_bounds__(256) void gemm_k(const float* __restrict__ A,
                                              const short* __restrict__ Bs,
                                              float* __restrict__ Lp,
                                              int atomic_mode) {
  const int tid = threadIdx.x;
  const int wave = tid >> 6, lane = tid & 63;
  const int l15 = lane & 15, quad = lane >> 4;
  const int m_base = blockIdx.x * 128 + wave * 32;
  const int kb = blockIdx.y;
  float* Lout = Lp + (atomic_mode ? (size_t)0 : (size_t)kb * NTOK * NEXP);

  const float* a0 = A + (size_t)(m_base + l15) * HDIM + kb * KSLICE + quad * 8;
  const float* a1 = a0 + (size_t)16 * HDIM;
  const short* bbase = Bs + ((size_t)(kb * NCHUNK) * 4 + quad) * 512 + l15 * 8;

  f32x4 acc[2][4];
#pragma unroll
  for (int mt = 0; mt < 2; ++mt)
#pragma unroll
    for (int nt = 0; nt < 4; ++nt) acc[mt][nt] = (f32x4){0.f, 0.f, 0.f, 0.f};

  float4 ra[2][2][2];  // [buf][mt][half]
  auto loadA = [&](int buf, int i) {
    ra[buf][0][0] = *(const float4*)(a0 + i * 32);
    ra[buf][0][1] = *(const float4*)(a0 + i * 32 + 4);
    ra[buf][1][0] = *(const float4*)(a1 + i * 32);
    ra[buf][1][1] = *(const float4*)(a1 + i * 32 + 4);
  };
  loadA(0, 0);

#pragma unroll 2
  for (int i = 0; i < NCHUNK; ++i) {
    const int cur = i & 1;
    if (i + 1 < NCHUNK) loadA(cur ^ 1, i + 1);  // prefetch next chunk
    short8 fa[2][3];
#pragma unroll
    for (int mt = 0; mt < 2; ++mt)
      split8(ra[cur][mt][0], ra[cur][mt][1], fa[mt][0], fa[mt][1], fa[mt][2]);
    const short* bc = bbase + (size_t)i * BT_KC;
#pragma unroll
    for (int nt = 0; nt < 4; ++nt) {
      const short8 bh = *(const short8*)(bc + nt * 128);
      const short8 bm = *(const short8*)(bc + nt * 128 + BT_TERM);
      const short8 bl = *(const short8*)(bc + nt * 128 + 2 * BT_TERM);
#pragma unroll
      for (int mt = 0; mt < 2; ++mt) {
        f32x4 c = acc[mt][nt];
        c = __builtin_amdgcn_mfma_f32_16x16x32_bf16(fa[mt][0], bh, c, 0, 0, 0);
        c = __builtin_amdgcn_mfma_f32_16x16x32_bf16(fa[mt][0], bm, c, 0, 0, 0);
        c = __builtin_amdgcn_mfma_f32_16x16x32_bf16(fa[mt][1], bh, c, 0, 0, 0);
        c = __builtin_amdgcn_mfma_f32_16x16x32_bf16(fa[mt][0], bl, c, 0, 0, 0);
        c = __builtin_amdgcn_mfma_f32_16x16x32_bf16(fa[mt][2], bh, c, 0, 0, 0);
        c = __builtin_amdgcn_mfma_f32_16x16x32_bf16(fa[mt][1], bm, c, 0, 0, 0);
        acc[mt][nt] = c;
      }
    }
  }

#pragma unroll
  for (int mt = 0; mt < 2; ++mt)
#pragma unroll
    for (int nt = 0; nt < 4; ++nt)
#pragma unroll
      for (int r = 0; r < 4; ++r) {
        const int m = m_base + mt * 16 + quad * 4 + r;
        const int n = nt * 16 + l15;
        if (atomic_mode) atomicAdd(&Lout[(size_t)m * NEXP + n], acc[mt][nt][r]);
        else Lout[(size_t)m * NEXP + n] = acc[mt][nt][r];
      }
}

// ---------------------------------------------------------------------------
// Top-k router, wave-per-token (lane = expert). rank via stable count,
// winners scatter via ds_permute. (unchanged from round 3 — it's ~8 us)
// ---------------------------------------------------------------------------
__global__ __launch_bounds__(256) void topk_k(const float* __restrict__ Lp, int nsl,
                                              float* __restrict__ out,
                                              float* __restrict__ auxbuf) {
  __shared__ float sl[4][64];
  __shared__ float s_aux[128];
  const int tid = threadIdx.x;
  const int wave = tid >> 6, lane = tid & 63;
  if (tid < 128) s_aux[tid] = 0.f;
  __syncthreads();

  for (int it = 0; it < TPW; ++it) {
    const int t = (blockIdx.x * 4 + wave) * TPW + it;
    float x = 0.f;
    for (int s = 0; s < nsl; ++s)
      x += Lp[(size_t)s * (NTOK * NEXP) + (size_t)t * NEXP + lane];
    sl[wave][lane] = x;

    float mx = x;
#pragma unroll
    for (int off = 32; off >= 1; off >>= 1)
      mx = fmaxf(mx, __shfl_xor(mx, off, 64));
    const float e = __expf(x - mx);
    float ssum = e;
#pragma unroll
    for (int off = 32; off >= 1; off >>= 1) ssum += __shfl_xor(ssum, off, 64);
    const float prob = e / ssum;

    __syncthreads();

    int cnt = 0;
#pragma unroll
    for (int c = 0; c < 4; ++c) {
      const float4 v0 = *(const float4*)&sl[wave][c * 16 + 0];
      const float4 v1 = *(const float4*)&sl[wave][c * 16 + 4];
      const float4 v2 = *(const float4*)&sl[wave][c * 16 + 8];
      const float4 v3 = *(const float4*)&sl[wave][c * 16 + 12];
      const float xv[16] = {v0.x, v0.y, v0.z, v0.w, v1.x, v1.y, v1.z, v1.w,
                            v2.x, v2.y, v2.z, v2.w, v3.x, v3.y, v3.z, v3.w};
#pragma unroll
      for (int j = 0; j < 16; ++j) {
        const int jj = c * 16 + j;
        cnt += (xv[j] > x) || (xv[j] == x && jj < lane);
      }
    }

    float tp = (cnt < 8) ? prob : 0.f;
    float tsum = tp;
#pragma unroll
    for (int off = 32; off >= 1; off >>= 1) tsum += __shfl_xor(tsum, off, 64);

    const int dst = cnt << 2;
    const float pv = __uint_as_float(
        (unsigned)__builtin_amdgcn_ds_permute(dst, (int)__float_as_uint(prob)));
    const int pi = __builtin_amdgcn_ds_permute(dst, lane);
    if (lane < 8) {
      out[(size_t)t * 8 + lane] = pv / tsum;
      out[(size_t)NTOK * 8 + (size_t)t * 8 + lane] = (float)pi;
    }
    atomicAdd(&s_aux[lane], prob);
    if (cnt < 8) atomicAdd(&s_aux[64 + lane], 1.f);
  }
  __syncthreads();
  if (tid < 128) atomicAdd(&auxbuf[(blockIdx.x & 7) * 128 + tid], s_aux[tid]);
}

// aux = E * sum_e (count_e/(T*K)) * (sumprob_e/T), over 8 auxbuf copies
__global__ void aux_k(const float* __restrict__ auxbuf, float* __restrict__ out) {
  const int e = threadIdx.x;
  float p = 0.f, f = 0.f;
#pragma unroll
  for (int c = 0; c < 8; ++c) {
    p += auxbuf[c * 128 + e];
    f += auxbuf[c * 128 + 64 + e];
  }
  p *= (1.f / (float)NTOK);
  f *= (1.f / ((float)NTOK * 8.f));
  float v = f * p;
#pragma unroll
  for (int off = 32; off >= 1; off >>= 1) v += __shfl_xor(v, off, 64);
  if (e == 0) out[2 * NTOK * 8] = 64.f * v;
}

extern "C" void kernel_launch(void* const* d_in, const int* in_sizes, int n_in,
                              void* d_out, int out_size, void* d_ws, size_t ws_size,
                              hipStream_t stream) {
  const float* hidden = (const float*)d_in[0];  // 8192 x 4096 fp32
  const float* gate = (const float*)d_in[1];    // 64 x 4096 fp32
  float* out = (float*)d_out;                   // [w 65536 | idx 65536 | aux 1]
  float* ws = (float*)d_ws;
  float* auxbuf = ws;  // 8 copies x 128 floats

  const size_t full_need =
      (size_t)AUXF * 4 + (size_t)KSPLIT * NTOK * NEXP * 4 + (size_t)3 * BT_TERM * 2;
  const int atomic_mode = (ws_size < full_need) ? 1 : 0;
  const int nsl = atomic_mode ? 1 : KSPLIT;
  float* slices = ws + AUXF;
  short* Bs = (short*)(ws + AUXF + (size_t)nsl * NTOK * NEXP);

  if (atomic_mode)
    hipMemsetAsync(slices, 0, (size_t)NTOK * NEXP * 4, stream);

  prep_k<<<129, 256, 0, stream>>>(gate, Bs, auxbuf);
  gemm_k<<<dim3(64, KSPLIT), 256, 0, stream>>>(hidden, Bs, slices, atomic_mode);
  topk_k<<<NTOK / (4 * TPW), 256, 0, stream>>>(slices, nsl, out, auxbuf);
  aux_k<<<1, 64, 0, stream>>>(auxbuf, out);
}